// Round 11
// baseline (258.998 us; speedup 1.0000x reference)
//
#include <hip/hip_runtime.h>
#include <math.h>

// ---------------- problem constants ----------------
#define BATCH 16
#define IH 384
#define IW 512
#define C1 10
#define P1H 191   // pooled H after conv1(382) / 2
#define P1W 255   // pooled W after conv1(510) / 2
#define P1S 256   // pool1 row stride (padded, 16B-aligned rows)
#define C2 16
#define H2 189
#define W2 253
#define C3 32
#define H3 187
#define W3 251
#define N3 (H3*W3)        // 46937
#define KP 128
#define CAP 7680          // max candidates kept for NMS (LDS-resident)
#define NEGV (-1e30f)

typedef _Float16 f16x8 __attribute__((ext_vector_type(8)));
typedef _Float16 f16x4 __attribute__((ext_vector_type(4)));
typedef float    f32x16 __attribute__((ext_vector_type(16)));

#define PXT 66            // conv3: staged px per block: 64 computed + 2 halo
#define PXT2 68           // conv2: staged px per block
#define NSUB 2            // 2 x 32-px MFMA sub-tiles per wave

// ------------- kernel 1: conv1+pool via MFMA (f16x2 split) -------------
// Round-11: conv1 moved onto the matrix pipe (3rd application of the proven
// pattern). K packs (ch,ky) = 9 of 16; kx taps = shifted LDS reads; maxpool
// folds into the epilogue: fmax over the two prepool-row acc sets (per-lane)
// + one __shfl_xor(1) across adjacent-px lanes. Bias after pool (uniform over
// window) then PReLU (monotone) == reference semantics.
// Ah/Al are fully zeroed before staging: k-slots 9..15 must be true zeros
// (0 x stale-NaN = NaN would poison the accumulator despite zero weights).
// Block (0,0,0) also pre-splits conv3+conv2 weights to global scratch.
__global__ __launch_bounds__(256, 2) void k_conv1mfma(
        const float* __restrict__ im, const float* __restrict__ w1,
        const float* __restrict__ b1, const float* __restrict__ s1,
        float* __restrict__ outp,                  // pool1, planar stride P1S
        const float* __restrict__ w3, const float* __restrict__ w2,
        _Float16* __restrict__ wbuf, _Float16* __restrict__ wbuf2) {
    __shared__ __align__(16) _Float16 Ah[4 * 130 * 16];   // 16640 B
    __shared__ __align__(16) _Float16 Al[4 * 130 * 16];   // 16640 B
    __shared__ __align__(16) _Float16 Wlds[2 * 1536];     // 6144 B (hi|lo)
    __shared__ float htab[20];                            // b1 | s1

    int tid = threadIdx.x;
    int bx = blockIdx.x, by = blockIdx.y, bb = blockIdx.z;

    if (bx == 0 && by == 0 && bb == 0) {
        // conv3 weights -> wbuf: [tap][kg][oc32][8ic] hi | lo
        for (int e = tid; e < 4608; e += 256) {
            int oc = e / 144;
            int rem = e - oc * 144;
            int ic = rem / 9;
            int tap = rem - ic * 9;
            float v = w3[e];
            _Float16 h = (_Float16)v;
            int d = ((tap * 2 + (ic >> 3)) * 32 + oc) * 8 + (ic & 7);
            wbuf[d] = h;
            wbuf[4608 + d] = (_Float16)(v - (float)h);
        }
        // conv2 weights -> wbuf2: [tap][half][oc32][8ic] hi | lo, zero-padded
        for (int e = tid; e < 4608; e += 256) {
            int tap = e / 512;
            int rem = e - tap * 512;
            int half = rem >> 8;
            int oc = (rem >> 3) & 31;
            int j = e & 7;
            int ic = half * 8 + j;
            float v = 0.f;
            if (oc < 16 && ic < 10) v = w2[(oc * 10 + ic) * 9 + tap];
            _Float16 h = (_Float16)v;
            wbuf2[e] = h;
            wbuf2[4608 + e] = (_Float16)(v - (float)h);
        }
    }

    // ---- phase 0: zero Ah/Al (1040 float4 each) ----
    {
        float4 z = make_float4(0.f, 0.f, 0.f, 0.f);
        for (int e = tid; e < 1040; e += 256) {
            ((float4*)Ah)[e] = z;
            ((float4*)Al)[e] = z;
        }
    }
    __syncthreads();

    // ---- phase 1: weights->LDS, htab, activations->LDS ----
    // conv1 weight fragments: [kx][half][oc32][8j], k=half*8+j=(ch*3+ky), padded
    for (int e = tid; e < 1536; e += 256) {
        int kx = e / 512;
        int rem = e & 511;
        int half = rem >> 8;
        int oc = (rem >> 3) & 31;
        int j = e & 7;
        int k = half * 8 + j;
        float v = 0.f;
        if (oc < C1 && k < 9) {
            int ch = k / 3, ky = k - ch * 3;
            v = w1[oc * 27 + ch * 9 + ky * 3 + kx];
        }
        _Float16 h = (_Float16)v;
        Wlds[e] = h;
        Wlds[1536 + e] = (_Float16)(v - (float)h);
    }
    if (tid < C1) { htab[tid] = b1[tid]; htab[10 + tid] = s1[tid]; }

    // stage: 6 input rows x 3 ch x 65 float2; value feeds granule rows
    // y = r-2..r (ky = r-y), k = ch*3+ky. Guards stage 0 (matches old tail=0).
    {
        const size_t ibase = (size_t)bb * 3 * IH * IW;
        int R0 = 4 * by, X0 = 128 * bx;
        for (int g = tid; g < 6 * 3 * 65; g += 256) {
            int r = g / 195;
            int rem = g - r * 195;
            int ch = rem / 65;
            int c2 = rem - ch * 65;
            int yg = R0 + r;
            int xg = X0 + 2 * c2;
            float2 v = make_float2(0.f, 0.f);
            if (yg < IH && xg < IW)   // xg even: xg<512 => xg+1<=511 in-bounds
                v = *(const float2*)(im + ibase + ((size_t)ch * IH + yg) * IW + xg);
            float a0 = (v.x - 127.5f) * 0.0078125f;
            float a1 = (v.y - 127.5f) * 0.0078125f;
            _Float16 h0 = (_Float16)a0, l0 = (_Float16)(a0 - (float)h0);
            _Float16 h1 = (_Float16)a1, l1 = (_Float16)(a1 - (float)h1);
            int px = 2 * c2;
            #pragma unroll
            for (int dy = 0; dy < 3; ++dy) {
                int y = r - dy;
                if (y >= 0 && y < 4) {
                    int k = ch * 3 + dy;
                    int i0 = (y * 130 + px) * 16 + k;
                    Ah[i0] = h0;      Al[i0] = l0;
                    Ah[i0 + 16] = h1; Al[i0 + 16] = l1;
                }
            }
        }
    }
    __syncthreads();

    // ---- phase 2: MFMA + pool + PReLU + store ----
    int wv = tid >> 6, lane = tid & 63;
    int col = lane & 31, half = lane >> 5;
    int pr = wv >> 1, cw = wv & 1;
    int PY = 2 * by + pr;
    if (PY >= P1H) return;          // no barriers below
    int y0 = 2 * pr, y1 = y0 + 1;

    const _Float16* WH = Wlds;
    const _Float16* WL = Wlds + 1536;

    #pragma unroll
    for (int s = 0; s < 2; ++s) {
        int pxs = cw * 64 + s * 32;
        f32x16 accA, accB;
        #pragma unroll
        for (int i = 0; i < 16; ++i) { accA[i] = 0.f; accB[i] = 0.f; }

        #pragma unroll
        for (int kx = 0; kx < 3; ++kx) {
            f16x8 wh = *(const f16x8*)(WH + ((kx * 2 + half) * 32 + col) * 8);
            f16x8 wl = *(const f16x8*)(WL + ((kx * 2 + half) * 32 + col) * 8);
            int p = pxs + col + kx;
            int i0 = (y0 * 130 + p) * 16 + half * 8;
            int i1 = (y1 * 130 + p) * 16 + half * 8;
            f16x8 ah0 = *(const f16x8*)(Ah + i0);
            f16x8 al0 = *(const f16x8*)(Al + i0);
            f16x8 ah1 = *(const f16x8*)(Ah + i1);
            f16x8 al1 = *(const f16x8*)(Al + i1);
            accA = __builtin_amdgcn_mfma_f32_32x32x16_f16(wh, ah0, accA, 0, 0, 0);
            accA = __builtin_amdgcn_mfma_f32_32x32x16_f16(wl, ah0, accA, 0, 0, 0);
            accA = __builtin_amdgcn_mfma_f32_32x32x16_f16(wh, al0, accA, 0, 0, 0);
            accB = __builtin_amdgcn_mfma_f32_32x32x16_f16(wh, ah1, accB, 0, 0, 0);
            accB = __builtin_amdgcn_mfma_f32_32x32x16_f16(wl, ah1, accB, 0, 0, 0);
            accB = __builtin_amdgcn_mfma_f32_32x32x16_f16(wh, al1, accB, 0, 0, 0);
        }

        // pool (y via per-lane max, x via shfl_xor(1)) -> bias -> PReLU -> store
        #pragma unroll
        for (int r = 0; r < 16; ++r) {
            int oc = (r & 3) + 8 * (r >> 2) + 4 * half;   // verified C-layout
            if (oc < C1) {
                float m = fmaxf(accA[r], accB[r]);
                float o = __shfl_xor(m, 1);
                m = fmaxf(m, o);
                if (!(col & 1)) {
                    int X = (128 * bx + pxs + col) >> 1;
                    if (X < P1W) {
                        float v = m + htab[oc];
                        float sl = htab[10 + oc];
                        v = v > 0.f ? v : sl * v;
                        outp[(((size_t)bb * C1 + oc) * P1H + PY) * P1S + X] = v;
                    }
                }
            }
        }
    }
}

// ------------- kernel 2: conv2 via MFMA (f16x2 split), NHWC output -------------
// Proven round-10: ic (10, padded 16) = K; taps = shifted LDS reads;
// [row][kg][px][8ic] conflict-free layout; M=16 of 32 oc (zero weights).
__global__ __launch_bounds__(256, 2) void k_conv2mfma(
        const float* __restrict__ pool1,          // planar [10][191][256]
        const _Float16* __restrict__ wbuf2,       // pre-split weights hi|lo
        const float* __restrict__ b2, const float* __restrict__ s2,
        float* __restrict__ outp) {               // NHWC fp32
    __shared__ __align__(16) _Float16 Ah[6 * 2 * PXT2 * 8];  // 13056 B
    __shared__ __align__(16) _Float16 Al[6 * 2 * PXT2 * 8];  // 13056 B
    __shared__ float htab[32];                                // b2 | s2

    int tid = threadIdx.x;
    int bx = blockIdx.x * 64;
    int by = blockIdx.y * 4;
    int bb = blockIdx.z;

    if (tid < 32) htab[tid] = (tid < 16) ? b2[tid] : s2[tid - 16];

    {
        const float* pin = pool1 + (size_t)bb * C1 * P1H * P1S;
        for (int e = tid; e < 6 * 16 * 17; e += 256) {
            int row = e / (16 * 17);
            int rem = e - row * (16 * 17);
            int ic  = rem / 17;
            int c4  = (rem - ic * 17) * 4;
            int yg = by + row;
            int xg = bx + c4;
            float4 v = make_float4(0.f, 0.f, 0.f, 0.f);
            if (ic < C1 && yg < P1H) {
                const float* src = pin + ((size_t)ic * P1H + yg) * P1S + xg;
                if (xg + 3 < P1W) v = *(const float4*)src;
                else {
                    if (xg     < P1W) v.x = src[0];
                    if (xg + 1 < P1W) v.y = src[1];
                    if (xg + 2 < P1W) v.z = src[2];
                }
            }
            int kg = ic >> 3, j = ic & 7;
            int base = ((row * 2 + kg) * PXT2 + c4) * 8 + j;
            _Float16 h;
            h = (_Float16)v.x; Ah[base]      = h; Al[base]      = (_Float16)(v.x - (float)h);
            h = (_Float16)v.y; Ah[base + 8]  = h; Al[base + 8]  = (_Float16)(v.y - (float)h);
            h = (_Float16)v.z; Ah[base + 16] = h; Al[base + 16] = (_Float16)(v.z - (float)h);
            h = (_Float16)v.w; Ah[base + 24] = h; Al[base + 24] = (_Float16)(v.w - (float)h);
        }
    }
    __syncthreads();

    int wv = tid >> 6, lane = tid & 63;
    int col = lane & 31, half = lane >> 5;
    int y = by + wv;
    if (y >= H2) return;          // no further barriers below

    f32x16 acc[NSUB];
    #pragma unroll
    for (int s = 0; s < NSUB; ++s)
        #pragma unroll
        for (int i = 0; i < 16; ++i) acc[s][i] = 0.f;

    const _Float16* wg = wbuf2 + (half * 32 + col) * 8;

    #pragma unroll 1
    for (int ky = 0; ky < 3; ++ky) {
        const _Float16* arh = Ah + ((wv + ky) * 2 + half) * (PXT2 * 8);
        const _Float16* arl = Al + ((wv + ky) * 2 + half) * (PXT2 * 8);
        #pragma unroll
        for (int kx = 0; kx < 3; ++kx) {
            int tap = ky * 3 + kx;
            f16x8 wh = *(const f16x8*)(wg + tap * 512);
            f16x8 wl = *(const f16x8*)(wg + 4608 + tap * 512);
            #pragma unroll
            for (int s = 0; s < NSUB; ++s) {
                int p = s * 32 + col + kx;
                f16x8 bh = *(const f16x8*)(arh + p * 8);
                f16x8 bl = *(const f16x8*)(arl + p * 8);
                acc[s] = __builtin_amdgcn_mfma_f32_32x32x16_f16(wh, bh, acc[s], 0, 0, 0);
                acc[s] = __builtin_amdgcn_mfma_f32_32x32x16_f16(wl, bh, acc[s], 0, 0, 0);
                acc[s] = __builtin_amdgcn_mfma_f32_32x32x16_f16(wh, bl, acc[s], 0, 0, 0);
            }
        }
    }

    int oc0 = 4 * half, oc1 = 8 + 4 * half;
    #pragma unroll
    for (int s = 0; s < NSUB; ++s) {
        int px = bx + s * 32 + col;
        if (px < W2) {
            float q[8];
            #pragma unroll
            for (int r = 0; r < 8; ++r) {
                int oc = (r < 4) ? (oc0 + r) : (oc1 + r - 4);
                float v = acc[s][r] + htab[oc];
                float sl = htab[16 + oc];
                q[r] = v > 0.f ? v : sl * v;
            }
            float* o = outp + (((size_t)bb * H2 + y) * W2 + px) * C2;
            *(float4*)(o + oc0) = make_float4(q[0], q[1], q[2], q[3]);
            *(float4*)(o + oc1) = make_float4(q[4], q[5], q[6], q[7]);
        }
    }
}

// ------------- kernel 3: conv3 via MFMA (f16x2 split) + heads -------------
__global__ __launch_bounds__(256, 2) void k_conv3mfma(
        const float* __restrict__ act,            // conv2 output, NHWC
        const _Float16* __restrict__ wbuf,        // pre-split weights hi|lo
        const float* __restrict__ b3, const float* __restrict__ s3,
        const float* __restrict__ w41, const float* __restrict__ b41,
        const float* __restrict__ w42, const float* __restrict__ b42,
        float* __restrict__ scores, float4* __restrict__ regf) {
    __shared__ __align__(16) _Float16 Ah[6 * 2 * PXT * 8];  // 12672 B
    __shared__ __align__(16) _Float16 Al[6 * 2 * PXT * 8];  // 12672 B
    __shared__ __align__(16) float    htab[32 * 8];          // 1024 B

    int tid = threadIdx.x;
    int bx = blockIdx.x * (NSUB * 32);
    int by = blockIdx.y * 4;
    int bb = blockIdx.z;

    {
        int oc = tid >> 3, f = tid & 7;
        float v;
        if      (f == 0) v = b3[oc];
        else if (f == 1) v = s3[oc];
        else if (f == 2) v = w41[oc];
        else if (f == 3) v = w41[32 + oc];
        else             v = w42[(f - 4) * 32 + oc];
        htab[tid] = v;
    }
    {
        const float* actb = act + (size_t)bb * H2 * W2 * C2;
        for (int e = tid; e < 6 * PXT * 4; e += 256) {
            int ic4 = e & 3;
            int t = e >> 2;
            int px = t % PXT;
            int row = t / PXT;
            int yg = by + row, xg = bx + px;
            float4 v = make_float4(0.f, 0.f, 0.f, 0.f);
            if (yg < H2 && xg < W2)
                v = *(const float4*)(actb + ((size_t)yg * W2 + xg) * C2 + ic4 * 4);
            float xs0 = v.x, xs1 = v.y, xs2 = v.z, xs3 = v.w;
            f16x4 hv, lv;
            _Float16 h;
            h = (_Float16)xs0; hv[0] = h; lv[0] = (_Float16)(xs0 - (float)h);
            h = (_Float16)xs1; hv[1] = h; lv[1] = (_Float16)(xs1 - (float)h);
            h = (_Float16)xs2; hv[2] = h; lv[2] = (_Float16)(xs2 - (float)h);
            h = (_Float16)xs3; hv[3] = h; lv[3] = (_Float16)(xs3 - (float)h);
            int kg = ic4 >> 1, h4 = ic4 & 1;
            int gr = (row * 2 + kg) * PXT + px;
            *(f16x4*)(Ah + gr * 8 + h4 * 4) = hv;
            *(f16x4*)(Al + gr * 8 + h4 * 4) = lv;
        }
    }
    __syncthreads();

    int wv = tid >> 6, lane = tid & 63;
    int col = lane & 31, half = lane >> 5;
    int y = by + wv;
    if (y >= H3) return;          // no further barriers below

    f32x16 acc[NSUB];
    #pragma unroll
    for (int s = 0; s < NSUB; ++s)
        #pragma unroll
        for (int i = 0; i < 16; ++i) acc[s][i] = 0.f;

    const _Float16* wg = wbuf + (half * 32 + col) * 8;

    #pragma unroll 1
    for (int ky = 0; ky < 3; ++ky) {
        const _Float16* arh = Ah + ((wv + ky) * 2 + half) * (PXT * 8);
        const _Float16* arl = Al + ((wv + ky) * 2 + half) * (PXT * 8);
        #pragma unroll
        for (int kx = 0; kx < 3; ++kx) {
            int tap = ky * 3 + kx;
            f16x8 wh = *(const f16x8*)(wg + tap * 512);
            f16x8 wl = *(const f16x8*)(wg + 4608 + tap * 512);
            #pragma unroll
            for (int s = 0; s < NSUB; ++s) {
                int p = s * 32 + col + kx;
                f16x8 bh = *(const f16x8*)(arh + p * 8);
                f16x8 bl = *(const f16x8*)(arl + p * 8);
                acc[s] = __builtin_amdgcn_mfma_f32_32x32x16_f16(wh, bh, acc[s], 0, 0, 0);
                acc[s] = __builtin_amdgcn_mfma_f32_32x32x16_f16(wl, bh, acc[s], 0, 0, 0);
                acc[s] = __builtin_amdgcn_mfma_f32_32x32x16_f16(wh, bl, acc[s], 0, 0, 0);
            }
        }
    }

    float L0[NSUB], L1[NSUB], R0[NSUB], R1[NSUB], R2[NSUB], R3[NSUB];
    #pragma unroll
    for (int s = 0; s < NSUB; ++s) { L0[s]=0.f; L1[s]=0.f; R0[s]=0.f; R1[s]=0.f; R2[s]=0.f; R3[s]=0.f; }

    #pragma unroll
    for (int r = 0; r < 16; ++r) {
        int oc = (r & 3) + 8 * (r >> 2) + 4 * half;   // verified 32x32 C-layout
        float4 t0 = *(const float4*)&htab[oc * 8];
        float4 t1 = *(const float4*)&htab[oc * 8 + 4];
        #pragma unroll
        for (int s = 0; s < NSUB; ++s) {
            float v = acc[s][r] + t0.x;
            v = v > 0.f ? v : v * t0.y;
            L0[s] += v * t0.z; L1[s] += v * t0.w;
            R0[s] += v * t1.x; R1[s] += v * t1.y;
            R2[s] += v * t1.z; R3[s] += v * t1.w;
        }
    }

    float hb0 = b41[0], hb1 = b41[1];
    float rb0 = b42[0], rb1 = b42[1], rb2 = b42[2], rb3 = b42[3];

    #pragma unroll
    for (int s = 0; s < NSUB; ++s) {
        float l0 = L0[s] + __shfl_xor(L0[s], 32) + hb0;
        float l1 = L1[s] + __shfl_xor(L1[s], 32) + hb1;
        float r0 = R0[s] + __shfl_xor(R0[s], 32) + rb0;
        float r1 = R1[s] + __shfl_xor(R1[s], 32) + rb1;
        float r2 = R2[s] + __shfl_xor(R2[s], 32) + rb2;
        float r3 = R3[s] + __shfl_xor(R3[s], 32) + rb3;
        float m = fmaxf(l0, l1);
        float e0 = expf(l0 - m), e1 = expf(l1 - m);
        float p = e1 / (e0 + e1);
        int px = bx + s * 32 + col;
        if (half == 0 && px < W3) {
            size_t n = (size_t)bb * N3 + (size_t)y * W3 + px;
            scores[n] = (p >= 0.6f) ? p : NEGV;
            regf[n] = make_float4(r0, r1, r2, r3);
        }
    }
}

// ------------- kernel 4: per-image NMS (LDS-resident) + box refine -------------
__global__ __launch_bounds__(512) void k_nms(
        const float* __restrict__ scores, const float4* __restrict__ regf,
        float* __restrict__ outp) {
    __shared__ float s_score[CAP];
    __shared__ int   s_idx[CAP];
    __shared__ float r_s[2][8];
    __shared__ int   r_i[2][8];
    __shared__ float s_picks[KP];
    __shared__ int   s_picki[KP];
    __shared__ int   s_misc[4];

    int tid = threadIdx.x;
    int bb = blockIdx.x;
    const float* sc = scores + (size_t)bb * N3;

    if (tid < 4) s_misc[tid] = 0;
    __syncthreads();

    int cnt = 0;
    for (int i = tid; i < N3; i += 512) if (sc[i] > 0.f) cnt++;
    atomicAdd(&s_misc[0], cnt);
    __syncthreads();
    int M = s_misc[0];

    int cutbin = 0;
    if (M > CAP) {
        for (int i = tid; i < 2048; i += 512) s_idx[i] = 0;
        __syncthreads();
        for (int i = tid; i < N3; i += 512) {
            float s = sc[i];
            if (s > 0.f) {
                int b = (int)((s - 0.6f) * 5120.f);
                b = b < 0 ? 0 : (b > 2047 ? 2047 : b);
                atomicAdd(&s_idx[b], 1);
            }
        }
        __syncthreads();
        if (tid == 0) {
            int accum = 0, b = 2047;
            for (; b >= 0; --b) {
                int c = s_idx[b];
                if (accum + c > CAP) break;
                accum += c;
            }
            s_misc[2] = b + 1;
        }
        __syncthreads();
        cutbin = s_misc[2];
        __syncthreads();
    }

    for (int i = tid; i < N3; i += 512) {
        float s = sc[i];
        if (s > 0.f) {
            bool keep = true;
            if (M > CAP) {
                int b = (int)((s - 0.6f) * 5120.f);
                b = b < 0 ? 0 : (b > 2047 ? 2047 : b);
                keep = (b >= cutbin);
            }
            if (keep) {
                int pos = atomicAdd(&s_misc[1], 1);
                if (pos < CAP) { s_score[pos] = s; s_idx[pos] = i; }
            }
        }
    }
    __syncthreads();
    int M2 = s_misc[1]; if (M2 > CAP) M2 = CAP;

    int np = 0;
    int   ppi = -1;
    float px1 = 0.f, py1 = 0.f, px2 = 0.f, py2 = 0.f;
    for (int pick = 0; pick < KP; ++pick) {
        float bs = -INFINITY; int bi = 0x7fffffff;
        for (int i = tid; i < M2; i += 512) {
            float s = s_score[i];
            if (ppi >= 0 && s > NEGV * 0.5f) {
                int id = s_idx[i];
                int cx = id % W3, cy = id / W3;
                float x1 = (float)(2 * cx + 1), y1 = (float)(2 * cy + 1);
                float x2 = (float)(2 * cx + 12), y2 = (float)(2 * cy + 12);
                float xx1 = fmaxf(px1, x1), yy1 = fmaxf(py1, y1);
                float xx2 = fminf(px2, x2), yy2 = fminf(py2, y2);
                float inter = fmaxf(0.f, xx2 - xx1 + 1.f) * fmaxf(0.f, yy2 - yy1 + 1.f);
                float iou = inter / (288.f - inter);
                if (iou > 0.5f) { s = NEGV; s_score[i] = NEGV; }
            }
            int id = s_idx[i];
            if (s > bs || (s == bs && id < bi)) { bs = s; bi = id; }
        }
        #pragma unroll
        for (int off = 32; off; off >>= 1) {
            float os = __shfl_down(bs, off);
            int   oi = __shfl_down(bi, off);
            if (os > bs || (os == bs && oi < bi)) { bs = os; bi = oi; }
        }
        int lane = tid & 63, wv = tid >> 6, buf = pick & 1;
        if (lane == 0) { r_s[buf][wv] = bs; r_i[buf][wv] = bi; }
        __syncthreads();
        float ps = r_s[buf][0]; int pi = r_i[buf][0];
        #pragma unroll
        for (int k = 1; k < 8; ++k) {
            float os = r_s[buf][k]; int oi = r_i[buf][k];
            if (os > ps || (os == ps && oi < pi)) { ps = os; pi = oi; }
        }
        if (ps < 0.f) break;
        if (tid == 0) { s_picks[pick] = ps; s_picki[pick] = pi; }
        np = pick + 1;

        ppi = pi;
        int pcx = pi % W3, pcy = pi / W3;
        px1 = (float)(2 * pcx + 1);  py1 = (float)(2 * pcy + 1);
        px2 = (float)(2 * pcx + 12); py2 = (float)(2 * pcy + 12);
    }
    __syncthreads();

    if (tid < KP) {
        float* o = outp + ((size_t)bb * KP + tid) * 5;
        if (tid < np) {
            int pi = s_picki[tid]; float ps = s_picks[tid];
            int cx = pi % W3, cy = pi / W3;
            float x1 = (float)(2 * cx + 1), y1 = (float)(2 * cy + 1);
            float x2 = (float)(2 * cx + 12), y2 = (float)(2 * cy + 12);
            float4 r = regf[(size_t)bb * N3 + pi];
            float wd = x2 - x1, hh = y2 - y1;
            float q1 = x1 + r.x * wd, q2 = y1 + r.y * hh;
            float q3 = x2 + r.z * wd, q4 = y2 + r.w * hh;
            float rw = q3 - q1, rh = q4 - q2;
            float L = fmaxf(rw, rh);
            float nx1 = q1 + rw * 0.5f - L * 0.5f;
            float ny1 = q2 + rh * 0.5f - L * 0.5f;
            o[0] = nx1; o[1] = ny1; o[2] = nx1 + L; o[3] = ny1 + L; o[4] = ps;
        } else {
            o[0] = 0.f; o[1] = 0.f; o[2] = 0.f; o[3] = 0.f; o[4] = 0.f;
        }
    }
}

// ---------------- launcher ----------------
extern "C" void kernel_launch(void* const* d_in, const int* in_sizes, int n_in,
                              void* d_out, int out_size, void* d_ws, size_t ws_size,
                              hipStream_t stream) {
    const float* im   = (const float*)d_in[0];
    const float* c1w  = (const float*)d_in[1];
    const float* c1b  = (const float*)d_in[2];
    const float* p1   = (const float*)d_in[3];
    const float* c2w  = (const float*)d_in[4];
    const float* c2b  = (const float*)d_in[5];
    const float* p2   = (const float*)d_in[6];
    const float* c3w  = (const float*)d_in[7];
    const float* c3b  = (const float*)d_in[8];
    const float* p3   = (const float*)d_in[9];
    const float* c41w = (const float*)d_in[10];
    const float* c41b = (const float*)d_in[11];
    const float* c42w = (const float*)d_in[12];
    const float* c42b = (const float*)d_in[13];

    float* ws = (float*)d_ws;
    const size_t P1FLOATS = (size_t)BATCH * C1 * P1H * P1S;       // 7,823,360
    float*  pool1   = ws;                                         // stride-256
    float*  conv2b  = ws + P1FLOATS;                              // NHWC
    float*  scoresb = ws;                                         // reuse region0
    float4* regfb   = (float4*)(ws + (size_t)BATCH * N3);         // 16B-aligned
    // weight hi/lo scratch in d_out (40960B): conv3 18432B + conv2 18432B;
    // k_nms overwrites d_out at the very end.
    _Float16* wbuf  = (_Float16*)d_out;
    _Float16* wbuf2 = wbuf + 9216;

    k_conv1mfma<<<dim3(4, 96, BATCH), dim3(256), 0, stream>>>(im, c1w, c1b, p1, pool1,
                                                              c3w, c2w, wbuf, wbuf2);
    k_conv2mfma<<<dim3(4, 48, BATCH), dim3(256), 0, stream>>>(pool1, wbuf2, c2b, p2, conv2b);
    k_conv3mfma<<<dim3(4, 47, BATCH), dim3(256), 0, stream>>>(conv2b, wbuf, c3b, p3,
                                                              c41w, c41b, c42w, c42b,
                                                              scoresb, regfb);
    k_nms<<<dim3(BATCH), dim3(512), 0, stream>>>(scoresb, regfb, (float*)d_out);
}